// Round 8
// baseline (432.562 us; speedup 1.0000x reference)
//
#include <hip/hip_runtime.h>

typedef _Float16 f16;
typedef f16 f16x8 __attribute__((ext_vector_type(8)));
typedef f16 f16x4 __attribute__((ext_vector_type(4)));
typedef float f32x4 __attribute__((ext_vector_type(4)));

#define QLEN 2048
#define BSZ 2
#define NH 16
#define DH 64
#define DM 1024
#define NBN (BSZ*NH)
#define SCALE 0.125f

static __device__ __forceinline__ f32x4 mfma16(f16x8 a, f16x8 b, f32x4 c) {
  return __builtin_amdgcn_mfma_f32_16x16x32_f16(a, b, c, 0, 0, 0);
}

// async global->LDS, 16B per lane; lds dest = wave-uniform base + lane*16
static __device__ __forceinline__ void gload_lds16(const void* g, void* l) {
  __builtin_amdgcn_global_load_lds((const __attribute__((address_space(1))) unsigned int*)g,
                                   (__attribute__((address_space(3))) unsigned int*)l,
                                   16, 0, 0);
}

// ---------------- K0a: fp32 -> fp16 convert ----------------
__global__ __launch_bounds__(256) void cvt_f32_f16(const float* __restrict__ s,
                                                   f16* __restrict__ d, int n4) {
  int idx = blockIdx.x * 256 + threadIdx.x;
  if (idx >= n4) return;
  f32x4 v = ((const f32x4*)s)[idx];
  f16x4 o;
#pragma unroll
  for (int q = 0; q < 4; ++q) o[q] = (f16)v[q];
  ((f16x4*)d)[idx] = o;
}

// ---------------- K0b: QKV GEMM  C[r][c] = sum_k hh[r][k]*wh[c][k] ----------
__global__ __launch_bounds__(256) void qkv_gemm(const f16* __restrict__ A, const f16* __restrict__ W,
                                                f16* __restrict__ Qs, f16* __restrict__ Ks,
                                                f16* __restrict__ Vt) {
  __shared__ f16 As[128 * 32];
  __shared__ f16 Bs[128 * 32];
  const int bid = blockIdx.x;
  const int r0 = (bid & 31) << 7;
  const int c0 = (bid >> 5) << 7;
  const int t = threadIdx.x;
  const int lane = t & 63, w = t >> 6;
  const int wr = (w >> 1) << 6, wc = (w & 1) << 6;
  const int l15 = lane & 15, lhi = lane >> 4;

  f32x4 acc[4][4] = {};

  const f16* ga = A + (size_t)(r0 + (t >> 2)) * DM + ((t & 3) << 3);
  const f16* gb = W + (size_t)(c0 + (t >> 2)) * DM + ((t & 3) << 3);
  char* la = (char*)As + w * 1024;
  char* lb = (char*)Bs + w * 1024;

  for (int k0 = 0; k0 < DM; k0 += 32) {
    __syncthreads();
    gload_lds16(ga + k0, la);
    gload_lds16(ga + k0 + (size_t)64 * DM, la + 4096);
    gload_lds16(gb + k0, lb);
    gload_lds16(gb + k0 + (size_t)64 * DM, lb + 4096);
    __syncthreads();
    f16x8 af[4], bf[4];
#pragma unroll
    for (int m = 0; m < 4; ++m)
      af[m] = *(const f16x8*)&As[(wr + m * 16 + l15) * 32 + lhi * 8];
#pragma unroll
    for (int n = 0; n < 4; ++n)
      bf[n] = *(const f16x8*)&Bs[(wc + n * 16 + l15) * 32 + lhi * 8];
#pragma unroll
    for (int m = 0; m < 4; ++m)
#pragma unroll
      for (int n = 0; n < 4; ++n)
        acc[m][n] = mfma16(af[m], bf[n], acc[m][n]);
  }

  const int part = c0 >> 10;  // uniform per block
#pragma unroll
  for (int m = 0; m < 4; ++m) {
#pragma unroll
    for (int n = 0; n < 4; ++n) {
#pragma unroll
      for (int q = 0; q < 4; ++q) {
        int r = r0 + wr + m * 16 + lhi * 4 + q;
        int c = c0 + wc + n * 16 + l15;
        int i = r >> 1, b = r & 1;
        int nh = (c >> 6) & 15, d = c & 63;
        int bn = b * 16 + nh;
        f16 v = (f16)acc[m][n][q];
        if (part == 0)       Qs[((size_t)bn * QLEN + i) * DH + d] = v;
        else if (part == 1)  Ks[((size_t)bn * QLEN + i) * DH + d] = v;
        else                 Vt[((size_t)bn * DH + d) * QLEN + i] = v;
      }
    }
  }
}

// ---------------- K1: flash attention -> attn_vec + row stats ----------------
__global__ __launch_bounds__(256) void flash_attn(const f16* __restrict__ Qs, const f16* __restrict__ Ks,
                                                  const f16* __restrict__ Vt, float* __restrict__ av,
                                                  float* __restrict__ sm, float* __restrict__ srl) {
  __shared__ f16 plds[4][16 * 32];
  const int bid = blockIdx.x;
  const int bn = bid >> 4, ib = bid & 15;
  const int t = threadIdx.x, lane = t & 63, w = t >> 6;
  const int l15 = lane & 15, lhi = lane >> 4;
  const int i0 = (ib << 7) + (w << 5);
  const f16* Qb = Qs + ((size_t)bn << 17);
  const f16* Kb = Ks + ((size_t)bn << 17);
  const f16* Vb = Vt + ((size_t)bn << 17);
  f16* pw = plds[w];

  f16x8 qf[2][2];
#pragma unroll
  for (int rg = 0; rg < 2; ++rg)
#pragma unroll
    for (int kc = 0; kc < 2; ++kc)
      qf[rg][kc] = *(const f16x8*)&Qb[(size_t)(i0 + rg * 16 + l15) * DH + kc * 32 + lhi * 8];

  f32x4 o[2][4] = {};
  float mrun[2][4], lrun[2][4];
#pragma unroll
  for (int rg = 0; rg < 2; ++rg)
#pragma unroll
    for (int q = 0; q < 4; ++q) { mrun[rg][q] = -1e30f; lrun[rg][q] = 0.f; }

  for (int j0 = 0; j0 < QLEN; j0 += 32) {
    f16x8 kf[2][2], vf[4];
#pragma unroll
    for (int jc = 0; jc < 2; ++jc)
#pragma unroll
      for (int kc = 0; kc < 2; ++kc)
        kf[jc][kc] = *(const f16x8*)&Kb[(size_t)(j0 + jc * 16 + l15) * DH + kc * 32 + lhi * 8];
#pragma unroll
    for (int dc = 0; dc < 4; ++dc)
      vf[dc] = *(const f16x8*)&Vb[(size_t)(dc * 16 + l15) * QLEN + j0 + lhi * 8];

#pragma unroll
    for (int rg = 0; rg < 2; ++rg) {
      f32x4 s[2];
#pragma unroll
      for (int jc = 0; jc < 2; ++jc) {
        f32x4 z = {0.f, 0.f, 0.f, 0.f};
        z = mfma16(qf[rg][0], kf[jc][0], z);
        z = mfma16(qf[rg][1], kf[jc][1], z);
        s[jc] = z;
      }
      float p[2][4], alpha[4];
#pragma unroll
      for (int q = 0; q < 4; ++q) {
        float v0 = s[0][q] * SCALE, v1 = s[1][q] * SCALE;
        float tm = fmaxf(v0, v1);
        tm = fmaxf(tm, __shfl_xor(tm, 1));
        tm = fmaxf(tm, __shfl_xor(tm, 2));
        tm = fmaxf(tm, __shfl_xor(tm, 4));
        tm = fmaxf(tm, __shfl_xor(tm, 8));
        float mnew = fmaxf(mrun[rg][q], tm);
        alpha[q] = __expf(mrun[rg][q] - mnew);
        mrun[rg][q] = mnew;
        p[0][q] = __expf(v0 - mnew);
        p[1][q] = __expf(v1 - mnew);
        float r = p[0][q] + p[1][q];
        r += __shfl_xor(r, 1);
        r += __shfl_xor(r, 2);
        r += __shfl_xor(r, 4);
        r += __shfl_xor(r, 8);
        lrun[rg][q] = lrun[rg][q] * alpha[q] + r;
      }
#pragma unroll
      for (int dc = 0; dc < 4; ++dc)
#pragma unroll
        for (int q = 0; q < 4; ++q)
          o[rg][dc][q] *= alpha[q];
#pragma unroll
      for (int jc = 0; jc < 2; ++jc)
#pragma unroll
        for (int q = 0; q < 4; ++q)
          pw[(lhi * 4 + q) * 32 + jc * 16 + l15] = (f16)p[jc][q];
      f16x8 pa = *(const f16x8*)&pw[l15 * 32 + lhi * 8];
#pragma unroll
      for (int dc = 0; dc < 4; ++dc)
        o[rg][dc] = mfma16(pa, vf[dc], o[rg][dc]);
    }
  }

  const int b = bn >> 4, nh = bn & 15;
#pragma unroll
  for (int rg = 0; rg < 2; ++rg)
#pragma unroll
    for (int dc = 0; dc < 4; ++dc)
#pragma unroll
      for (int q = 0; q < 4; ++q) {
        int i = i0 + rg * 16 + lhi * 4 + q;
        av[((size_t)i * BSZ + b) * (NH * DH) + nh * DH + dc * 16 + l15] =
            o[rg][dc][q] / lrun[rg][q];
      }
  if (l15 == 0) {
#pragma unroll
    for (int rg = 0; rg < 2; ++rg)
#pragma unroll
      for (int q = 0; q < 4; ++q) {
        int i = i0 + rg * 16 + lhi * 4 + q;
        sm[bn * QLEN + i] = mrun[rg][q];
        srl[bn * QLEN + i] = 1.0f / lrun[rg][q];
      }
  }
}

// ---------------- K2: materialize attn_prob [i][j][b][n] ----------------
// R8: DRAM-row-locality theory. Single 64KB LDS tile [16i][64j][32bn] f16;
// per block 4 super-chunks of j-span 64. Store phase writes 16 rows x 8KB
// CONTIGUOUS nt bursts (2x R6's 4KB). Barrier #1 (before deposit) drains
// prior chunk's stores -- issued one full compute phase earlier, so cheap.
// Compute is R6's proven structure (R7 pipelining reverted).
__global__ __launch_bounds__(256, 2) void write_probs(const f16* __restrict__ Qs, const f16* __restrict__ Ks,
                                                      const float* __restrict__ sm, const float* __restrict__ srl,
                                                      float* __restrict__ pout) {
  __shared__ f16 tile[16 * 64 * 32];     // 64 KiB
  const int bid = blockIdx.x;            // 1024 blocks
  const int it = bid >> 3, jt = bid & 7; // bid%8 -> XCD-local K panel
  const int i0 = it << 4, j0 = jt << 8;
  const int t = threadIdx.x, lane = t & 63, w = t >> 6;
  const int l15 = lane & 15, lhi = lane >> 4;

  // store-phase lane mapping (constant across chunks)
  const int o = t & 3;             // bn octet 0..3
  const int j_s = t >> 2;          // j within 64-span, 0..63
  const int sp = o ^ ((j_s & 7) >> 1);  // b128 slot-pair index
  const bool hsw = (j_s & 1);

  for (int sc = 0; sc < 4; ++sc) {
    const int jbase = j0 + sc * 64;

    f16x4 stv[8][4];  // [bl][jc], packed over q
#pragma unroll
    for (int bl = 0; bl < 8; ++bl) {
      const int bn = w * 8 + bl;
      const f16* Qb = Qs + ((size_t)bn << 17);
      const f16* Kb = Ks + ((size_t)bn << 17);
      f16x8 qf[2], kf[4][2];
#pragma unroll
      for (int kc = 0; kc < 2; ++kc)
        qf[kc] = *(const f16x8*)&Qb[(size_t)(i0 + l15) * DH + kc * 32 + lhi * 8];
#pragma unroll
      for (int jc = 0; jc < 4; ++jc)
#pragma unroll
        for (int kc = 0; kc < 2; ++kc)
          kf[jc][kc] = *(const f16x8*)&Kb[(size_t)(jbase + jc * 16 + l15) * DH + kc * 32 + lhi * 8];
      float mm[4], rl[4];
#pragma unroll
      for (int q = 0; q < 4; ++q) {
        const int i = i0 + lhi * 4 + q;
        mm[q] = sm[bn * QLEN + i];
        rl[q] = srl[bn * QLEN + i];
      }
#pragma unroll
      for (int jc = 0; jc < 4; ++jc) {
        f32x4 z = {0.f, 0.f, 0.f, 0.f};
        z = mfma16(qf[0], kf[jc][0], z);
        z = mfma16(qf[1], kf[jc][1], z);
#pragma unroll
        for (int q = 0; q < 4; ++q)
          stv[bl][jc][q] = (f16)(__expf(z[q] * SCALE - mm[q]) * rl[q]);
      }
    }

    // barrier #1: all waves done reading LDS for previous chunk's stores
    // (also drains prior stores, issued one compute-phase ago -> cheap)
    __syncthreads();

    // deposit: 32 x ds_write_b64; granule g = bn>>2 at position g ^ (jl&7)
#pragma unroll
    for (int h = 0; h < 2; ++h) {
      const int g = w * 2 + h;
#pragma unroll
      for (int jc = 0; jc < 4; ++jc)
#pragma unroll
        for (int q = 0; q < 4; ++q) {
          const int i_l = lhi * 4 + q;
          const int jl = jc * 16 + l15;
          f16x4 v = {stv[4 * h + 0][jc][q], stv[4 * h + 1][jc][q],
                     stv[4 * h + 2][jc][q], stv[4 * h + 3][jc][q]};
          *(f16x4*)&tile[(i_l * 64 + jl) * 32 + ((g ^ (jl & 7)) << 2)] = v;
        }
    }
    __syncthreads();

    // store: 16 passes; each pass = one i-row = 8KB fully contiguous
    // (256 threads x 32B). nt stores, fire-and-forget.
#pragma unroll
    for (int r = 0; r < 16; ++r) {
      f16x8 v = *(const f16x8*)&tile[(r * 64 + j_s) * 32 + (sp << 3)];
      f16x4 vl = {v[0], v[1], v[2], v[3]};
      f16x4 vh = {v[4], v[5], v[6], v[7]};
      f16x4 fa = hsw ? vh : vl;
      f16x4 fb = hsw ? vl : vh;
      f32x4 lo = {(float)fa[0], (float)fa[1], (float)fa[2], (float)fa[3]};
      f32x4 hi = {(float)fb[0], (float)fb[1], (float)fb[2], (float)fb[3]};
      float* op = pout + ((size_t)(i0 + r) * QLEN + jbase + j_s) * NBN + o * 8;
      __builtin_nontemporal_store(lo, (f32x4*)op);
      __builtin_nontemporal_store(hi, (f32x4*)(op + 4));
    }
  }
}

// ---------------- launcher ----------------
extern "C" void kernel_launch(void* const* d_in, const int* in_sizes, int n_in,
                              void* d_out, int out_size, void* d_ws, size_t ws_size,
                              hipStream_t stream) {
  const float* h  = (const float*)d_in[0];
  const float* wq = (const float*)d_in[1];
  float* av   = (float*)d_out;
  float* pout = av + (size_t)QLEN * BSZ * NH * DH;

  char* ws = (char*)d_ws;
  f16* hh  = (f16*)ws;                        // 8 MiB
  f16* wh  = (f16*)(ws + (8u << 20));         // 6 MiB
  f16* Qsc = (f16*)(ws + (16u << 20));        // 8 MiB
  f16* Ksc = (f16*)(ws + (24u << 20));        // 8 MiB
  f16* Vtc = (f16*)(ws + (32u << 20));        // 8 MiB
  float* smv  = (float*)(ws + (40u << 20));
  float* srlv = (float*)(ws + (40u << 20) + (QLEN * NBN * 4));

  const int nh4 = QLEN * BSZ * DM / 4;
  const int nw4 = 3 * NH * DH * DM / 4;
  cvt_f32_f16<<<nh4 / 256, 256, 0, stream>>>(h, hh, nh4);
  cvt_f32_f16<<<nw4 / 256, 256, 0, stream>>>(wq, wh, nw4);
  qkv_gemm<<<32 * 24, 256, 0, stream>>>(hh, wh, Qsc, Ksc, Vtc);
  flash_attn<<<NBN * 16, 256, 0, stream>>>(Qsc, Ksc, Vtc, av, smv, srlv);
  write_probs<<<128 * 8, 256, 0, stream>>>(Qsc, Ksc, smv, srlv, pout);
}

// Round 9
// 387.973 us; speedup vs baseline: 1.1149x; 1.1149x over previous
//
#include <hip/hip_runtime.h>

typedef _Float16 f16;
typedef f16 f16x8 __attribute__((ext_vector_type(8)));
typedef f16 f16x4 __attribute__((ext_vector_type(4)));
typedef float f32x4 __attribute__((ext_vector_type(4)));

#define QLEN 2048
#define BSZ 2
#define NH 16
#define DH 64
#define DM 1024
#define NBN (BSZ*NH)
#define SCALE 0.125f

static __device__ __forceinline__ f32x4 mfma16(f16x8 a, f16x8 b, f32x4 c) {
  return __builtin_amdgcn_mfma_f32_16x16x32_f16(a, b, c, 0, 0, 0);
}

// async global->LDS, 16B per lane; lds dest = wave-uniform base + lane*16
static __device__ __forceinline__ void gload_lds16(const void* g, void* l) {
  __builtin_amdgcn_global_load_lds((const __attribute__((address_space(1))) unsigned int*)g,
                                   (__attribute__((address_space(3))) unsigned int*)l,
                                   16, 0, 0);
}

// ---------------- K0a: fp32 -> fp16 convert ----------------
__global__ __launch_bounds__(256) void cvt_f32_f16(const float* __restrict__ s,
                                                   f16* __restrict__ d, int n4) {
  int idx = blockIdx.x * 256 + threadIdx.x;
  if (idx >= n4) return;
  f32x4 v = ((const f32x4*)s)[idx];
  f16x4 o;
#pragma unroll
  for (int q = 0; q < 4; ++q) o[q] = (f16)v[q];
  ((f16x4*)d)[idx] = o;
}

// ---------------- K0b: QKV GEMM  C[r][c] = sum_k hh[r][k]*wh[c][k] ----------
// R9: BK=64 (half the barriers, 32 MFMA/step); granule-XOR pre-swizzled
// global staging (linear gload_lds dest, swizzled ds_read -> <=2-way
// conflicts); epilogue stages tile through LDS into output-major layout,
// stores 128B contiguous per thread (kills the 2B-scatter, esp. for Vt).
__global__ __launch_bounds__(256) void qkv_gemm(const f16* __restrict__ A, const f16* __restrict__ W,
                                                f16* __restrict__ Qs, f16* __restrict__ Ks,
                                                f16* __restrict__ Vt) {
  __shared__ f16 S[2][128 * 64];  // As=S[0], Bs=S[1]; reused by epilogue
  f16* As = S[0];
  f16* Bs = S[1];
  const int bid = blockIdx.x;
  const int r0 = (bid & 31) << 7;
  const int c0 = (bid >> 5) << 7;
  const int t = threadIdx.x;
  const int lane = t & 63, w = t >> 6;
  const int wr = (w >> 1) << 6, wc = (w & 1) << 6;
  const int l15 = lane & 15, lhi = lane >> 4;

  f32x4 acc[4][4] = {};

  // staging: thread t owns LDS slot (row=t>>3 (+32*it), granule=t&7);
  // source col granule pre-swizzled by row&7 so swizzled reads see linear data
  const int scol = (((t & 7) ^ ((t >> 3) & 7)) << 3);
  const f16* ga = A + (size_t)(r0 + (t >> 3)) * DM + scol;
  const f16* gb = W + (size_t)(c0 + (t >> 3)) * DM + scol;
  char* la = (char*)As + w * 1024;
  char* lb = (char*)Bs + w * 1024;

  for (int k0 = 0; k0 < DM; k0 += 64) {
    __syncthreads();
#pragma unroll
    for (int it = 0; it < 4; ++it) {
      gload_lds16(ga + k0 + (size_t)(it * 32) * DM, la + it * 4096);
      gload_lds16(gb + k0 + (size_t)(it * 32) * DM, lb + it * 4096);
    }
    __syncthreads();
#pragma unroll
    for (int kk = 0; kk < 2; ++kk) {
      f16x8 af[4], bf[4];
#pragma unroll
      for (int m = 0; m < 4; ++m) {
        const int r = wr + m * 16 + l15;
        af[m] = *(const f16x8*)&As[r * 64 + (((kk * 4 + lhi) ^ (r & 7)) << 3)];
      }
#pragma unroll
      for (int n = 0; n < 4; ++n) {
        const int r = wc + n * 16 + l15;
        bf[n] = *(const f16x8*)&Bs[r * 64 + (((kk * 4 + lhi) ^ (r & 7)) << 3)];
      }
#pragma unroll
      for (int m = 0; m < 4; ++m)
#pragma unroll
        for (int n = 0; n < 4; ++n)
          acc[m][n] = mfma16(af[m], bf[n], acc[m][n]);
    }
  }

  // ---- epilogue: LDS-staged transpose to output-major, 128B/thread stores
  const int part = c0 >> 10;            // 0=Q 1=K 2=V, uniform per block
  const int nh_base = (c0 >> 6) & 15;
  const int i0g = r0 >> 1;
  f16* T = (f16*)S;                     // 256*64 f16 = 32KB

  __syncthreads();  // main-loop LDS reads finished everywhere
#pragma unroll
  for (int m = 0; m < 4; ++m)
#pragma unroll
    for (int n = 0; n < 4; ++n)
#pragma unroll
      for (int q = 0; q < 4; ++q) {
        const int r_l = wr + m * 16 + lhi * 4 + q;
        const int c_l = wc + n * 16 + l15;
        const int i_l = r_l >> 1, b = r_l & 1;
        const int nh_l = c_l >> 6, d = c_l & 63;
        const int bn2 = b * 2 + nh_l;
        const f16 v = (f16)acc[m][n][q];
        if (part < 2) T[(bn2 * 64 + i_l) * 64 + (d ^ ((i_l & 7) << 3))] = v;
        else          T[(bn2 * 64 + d) * 64 + (i_l ^ ((d & 7) << 3))] = v;
      }
  __syncthreads();

  // store: thread t owns (bn2 = t>>6, x = t&63); 8 x 16B = 128B contiguous
  {
    const int bn2 = t >> 6, x = t & 63;
    const int bn = (bn2 >> 1) * 16 + nh_base + (bn2 & 1);
    f16* dst;
    if (part == 0)      dst = Qs + ((size_t)bn * QLEN + i0g + x) * DH;
    else if (part == 1) dst = Ks + ((size_t)bn * QLEN + i0g + x) * DH;
    else                dst = Vt + ((size_t)bn * DH + x) * QLEN + i0g;
    const f16* src = &T[(bn2 * 64 + x) * 64];
#pragma unroll
    for (int g = 0; g < 8; ++g)
      *(f16x8*)&dst[g * 8] = *(const f16x8*)&src[(g ^ (x & 7)) << 3];
  }
}

// ---------------- K1: flash attention -> attn_vec + row stats ----------------
__global__ __launch_bounds__(256) void flash_attn(const f16* __restrict__ Qs, const f16* __restrict__ Ks,
                                                  const f16* __restrict__ Vt, float* __restrict__ av,
                                                  float* __restrict__ sm, float* __restrict__ srl) {
  __shared__ f16 plds[4][16 * 32];
  const int bid = blockIdx.x;
  const int bn = bid >> 4, ib = bid & 15;
  const int t = threadIdx.x, lane = t & 63, w = t >> 6;
  const int l15 = lane & 15, lhi = lane >> 4;
  const int i0 = (ib << 7) + (w << 5);
  const f16* Qb = Qs + ((size_t)bn << 17);
  const f16* Kb = Ks + ((size_t)bn << 17);
  const f16* Vb = Vt + ((size_t)bn << 17);
  f16* pw = plds[w];

  f16x8 qf[2][2];
#pragma unroll
  for (int rg = 0; rg < 2; ++rg)
#pragma unroll
    for (int kc = 0; kc < 2; ++kc)
      qf[rg][kc] = *(const f16x8*)&Qb[(size_t)(i0 + rg * 16 + l15) * DH + kc * 32 + lhi * 8];

  f32x4 o[2][4] = {};
  float mrun[2][4], lrun[2][4];
#pragma unroll
  for (int rg = 0; rg < 2; ++rg)
#pragma unroll
    for (int q = 0; q < 4; ++q) { mrun[rg][q] = -1e30f; lrun[rg][q] = 0.f; }

  for (int j0 = 0; j0 < QLEN; j0 += 32) {
    f16x8 kf[2][2], vf[4];
#pragma unroll
    for (int jc = 0; jc < 2; ++jc)
#pragma unroll
      for (int kc = 0; kc < 2; ++kc)
        kf[jc][kc] = *(const f16x8*)&Kb[(size_t)(j0 + jc * 16 + l15) * DH + kc * 32 + lhi * 8];
#pragma unroll
    for (int dc = 0; dc < 4; ++dc)
      vf[dc] = *(const f16x8*)&Vb[(size_t)(dc * 16 + l15) * QLEN + j0 + lhi * 8];

#pragma unroll
    for (int rg = 0; rg < 2; ++rg) {
      f32x4 s[2];
#pragma unroll
      for (int jc = 0; jc < 2; ++jc) {
        f32x4 z = {0.f, 0.f, 0.f, 0.f};
        z = mfma16(qf[rg][0], kf[jc][0], z);
        z = mfma16(qf[rg][1], kf[jc][1], z);
        s[jc] = z;
      }
      float p[2][4], alpha[4];
#pragma unroll
      for (int q = 0; q < 4; ++q) {
        float v0 = s[0][q] * SCALE, v1 = s[1][q] * SCALE;
        float tm = fmaxf(v0, v1);
        tm = fmaxf(tm, __shfl_xor(tm, 1));
        tm = fmaxf(tm, __shfl_xor(tm, 2));
        tm = fmaxf(tm, __shfl_xor(tm, 4));
        tm = fmaxf(tm, __shfl_xor(tm, 8));
        float mnew = fmaxf(mrun[rg][q], tm);
        alpha[q] = __expf(mrun[rg][q] - mnew);
        mrun[rg][q] = mnew;
        p[0][q] = __expf(v0 - mnew);
        p[1][q] = __expf(v1 - mnew);
        float r = p[0][q] + p[1][q];
        r += __shfl_xor(r, 1);
        r += __shfl_xor(r, 2);
        r += __shfl_xor(r, 4);
        r += __shfl_xor(r, 8);
        lrun[rg][q] = lrun[rg][q] * alpha[q] + r;
      }
#pragma unroll
      for (int dc = 0; dc < 4; ++dc)
#pragma unroll
        for (int q = 0; q < 4; ++q)
          o[rg][dc][q] *= alpha[q];
#pragma unroll
      for (int jc = 0; jc < 2; ++jc)
#pragma unroll
        for (int q = 0; q < 4; ++q)
          pw[(lhi * 4 + q) * 32 + jc * 16 + l15] = (f16)p[jc][q];
      f16x8 pa = *(const f16x8*)&pw[l15 * 32 + lhi * 8];
#pragma unroll
      for (int dc = 0; dc < 4; ++dc)
        o[rg][dc] = mfma16(pa, vf[dc], o[rg][dc]);
    }
  }

  const int b = bn >> 4, nh = bn & 15;
#pragma unroll
  for (int rg = 0; rg < 2; ++rg)
#pragma unroll
    for (int dc = 0; dc < 4; ++dc)
#pragma unroll
      for (int q = 0; q < 4; ++q) {
        int i = i0 + rg * 16 + lhi * 4 + q;
        av[((size_t)i * BSZ + b) * (NH * DH) + nh * DH + dc * 16 + l15] =
            o[rg][dc][q] / lrun[rg][q];
      }
  if (l15 == 0) {
#pragma unroll
    for (int rg = 0; rg < 2; ++rg)
#pragma unroll
      for (int q = 0; q < 4; ++q) {
        int i = i0 + rg * 16 + lhi * 4 + q;
        sm[bn * QLEN + i] = mrun[rg][q];
        srl[bn * QLEN + i] = 1.0f / lrun[rg][q];
      }
  }
}

// ---------------- K2: materialize attn_prob [i][j][b][n] ----------------
// R6-exact (best measured: wp ~= 228us). TI=16, TJ=256; 8 j-chunks of 32;
// f16 probs through 2x32KB double-buffered LDS; whole-128B-line nt stores.
__global__ __launch_bounds__(256, 2) void write_probs(const f16* __restrict__ Qs, const f16* __restrict__ Ks,
                                                      const float* __restrict__ sm, const float* __restrict__ srl,
                                                      float* __restrict__ pout) {
  __shared__ f16 tile[2][16 * 32 * 32];  // 2 x 32 KiB
  const int bid = blockIdx.x;            // 1024 blocks
  const int it = bid >> 3, jt = bid & 7; // jt%8 -> XCD-local K panel
  const int i0 = it << 4, j0 = jt << 8;
  const int t = threadIdx.x, lane = t & 63, w = t >> 6;
  const int l15 = lane & 15, lhi = lane >> 4;

  // persistent row stats for this wave's 8 bn (broadcast loads)
  float mm[8][4], rl[8][4];
#pragma unroll
  for (int bl = 0; bl < 8; ++bl) {
    const int bn = w * 8 + bl;
#pragma unroll
    for (int q = 0; q < 4; ++q) {
      const int i = i0 + lhi * 4 + q;
      mm[bl][q] = sm[bn * QLEN + i];
      rl[bl][q] = srl[bn * QLEN + i];
    }
  }

  // store-phase lane mapping (constant across chunks)
  const int o = t & 3;             // bn octet 0..3
  const int jl_s = (t >> 2) & 31;  // j within chunk
  const int ihalf = t >> 7;        // i parity
  const int quad = o ^ ((jl_s & 7) >> 1);
  const bool hsw = (jl_s & 1);

  for (int ch = 0; ch < 8; ++ch) {
    f16* tb = tile[ch & 1];
    const int jbase = j0 + ch * 32;

    f16 stv[8][2][4];
#pragma unroll
    for (int bl = 0; bl < 8; ++bl) {
      const int bn = w * 8 + bl;
      const f16* Qb = Qs + ((size_t)bn << 17);
      const f16* Kb = Ks + ((size_t)bn << 17);
      f16x8 qf[2], kf[2][2];
#pragma unroll
      for (int kc = 0; kc < 2; ++kc)
        qf[kc] = *(const f16x8*)&Qb[(size_t)(i0 + l15) * DH + kc * 32 + lhi * 8];
#pragma unroll
      for (int jc = 0; jc < 2; ++jc)
#pragma unroll
        for (int kc = 0; kc < 2; ++kc)
          kf[jc][kc] = *(const f16x8*)&Kb[(size_t)(jbase + jc * 16 + l15) * DH + kc * 32 + lhi * 8];
#pragma unroll
      for (int jc = 0; jc < 2; ++jc) {
        f32x4 z = {0.f, 0.f, 0.f, 0.f};
        z = mfma16(qf[0], kf[jc][0], z);
        z = mfma16(qf[1], kf[jc][1], z);
#pragma unroll
        for (int q = 0; q < 4; ++q)
          stv[bl][jc][q] = (f16)(__expf(z[q] * SCALE - mm[bl][q]) * rl[bl][q]);
      }
    }

    // deposit: 16 x ds_write_b64; granule g = bn>>2 at position g ^ (jl&7)
#pragma unroll
    for (int h = 0; h < 2; ++h) {
      const int g = w * 2 + h;
#pragma unroll
      for (int jc = 0; jc < 2; ++jc)
#pragma unroll
        for (int q = 0; q < 4; ++q) {
          const int i_l = lhi * 4 + q;
          const int jl = jc * 16 + l15;
          f16x4 v = {stv[4 * h + 0][jc][q], stv[4 * h + 1][jc][q],
                     stv[4 * h + 2][jc][q], stv[4 * h + 3][jc][q]};
          *(f16x4*)&tb[(i_l * 32 + jl) * 32 + ((g ^ (jl & 7)) << 2)] = v;
        }
    }
    __syncthreads();

    // store: 8 passes; 4 lanes complete each 128B line; nt stores drain
    // under next chunk's compute (double buffer, no trailing barrier)
#pragma unroll
    for (int p = 0; p < 8; ++p) {
      const int i_l = p * 2 + ihalf;
      f16x8 v = *(const f16x8*)&tb[(i_l * 32 + jl_s) * 32 + (quad << 3)];
      f16x4 vl = {v[0], v[1], v[2], v[3]};
      f16x4 vh = {v[4], v[5], v[6], v[7]};
      f16x4 fa = hsw ? vh : vl;
      f16x4 fb = hsw ? vl : vh;
      f32x4 lo = {(float)fa[0], (float)fa[1], (float)fa[2], (float)fa[3]};
      f32x4 hi = {(float)fb[0], (float)fb[1], (float)fb[2], (float)fb[3]};
      float* op = pout + ((size_t)(i0 + i_l) * QLEN + jbase + jl_s) * NBN + o * 8;
      __builtin_nontemporal_store(lo, (f32x4*)op);
      __builtin_nontemporal_store(hi, (f32x4*)(op + 4));
    }
  }
}

// ---------------- launcher ----------------
extern "C" void kernel_launch(void* const* d_in, const int* in_sizes, int n_in,
                              void* d_out, int out_size, void* d_ws, size_t ws_size,
                              hipStream_t stream) {
  const float* h  = (const float*)d_in[0];
  const float* wq = (const float*)d_in[1];
  float* av   = (float*)d_out;
  float* pout = av + (size_t)QLEN * BSZ * NH * DH;

  char* ws = (char*)d_ws;
  f16* hh  = (f16*)ws;                        // 8 MiB
  f16* wh  = (f16*)(ws + (8u << 20));         // 6 MiB
  f16* Qsc = (f16*)(ws + (16u << 20));        // 8 MiB
  f16* Ksc = (f16*)(ws + (24u << 20));        // 8 MiB
  f16* Vtc = (f16*)(ws + (32u << 20));        // 8 MiB
  float* smv  = (float*)(ws + (40u << 20));
  float* srlv = (float*)(ws + (40u << 20) + (QLEN * NBN * 4));

  const int nh4 = QLEN * BSZ * DM / 4;
  const int nw4 = 3 * NH * DH * DM / 4;
  cvt_f32_f16<<<nh4 / 256, 256, 0, stream>>>(h, hh, nh4);
  cvt_f32_f16<<<nw4 / 256, 256, 0, stream>>>(wq, wh, nw4);
  qkv_gemm<<<32 * 24, 256, 0, stream>>>(hh, wh, Qsc, Ksc, Vtc);
  flash_attn<<<NBN * 16, 256, 0, stream>>>(Qsc, Ksc, Vtc, av, smv, srlv);
  write_probs<<<128 * 8, 256, 0, stream>>>(Qsc, Ksc, smv, srlv, pout);
}

// Round 10
// 387.485 us; speedup vs baseline: 1.1163x; 1.0013x over previous
//
#include <hip/hip_runtime.h>

typedef _Float16 f16;
typedef f16 f16x8 __attribute__((ext_vector_type(8)));
typedef f16 f16x4 __attribute__((ext_vector_type(4)));
typedef float f32x4 __attribute__((ext_vector_type(4)));

#define QLEN 2048
#define BSZ 2
#define NH 16
#define DH 64
#define DM 1024
#define NBN (BSZ*NH)
#define SCALE 0.125f

static __device__ __forceinline__ f32x4 mfma16(f16x8 a, f16x8 b, f32x4 c) {
  return __builtin_amdgcn_mfma_f32_16x16x32_f16(a, b, c, 0, 0, 0);
}

// async global->LDS, 16B per lane; lds dest = wave-uniform base + lane*16
static __device__ __forceinline__ void gload_lds16(const void* g, void* l) {
  __builtin_amdgcn_global_load_lds((const __attribute__((address_space(1))) unsigned int*)g,
                                   (__attribute__((address_space(3))) unsigned int*)l,
                                   16, 0, 0);
}

// LDS-only barrier: waits ds ops (lgkmcnt) but does NOT drain global stores
// (__syncthreads would emit s_waitcnt vmcnt(0) before s_barrier, stalling on
// every outstanding nt store -- the R6-R8 plateau mechanism).
static __device__ __forceinline__ void barrier_lds() {
  __builtin_amdgcn_sched_barrier(0);
  asm volatile("s_waitcnt lgkmcnt(0)" ::: "memory");
  __builtin_amdgcn_s_barrier();
  __builtin_amdgcn_sched_barrier(0);
}

// ---------------- K0a: fp32 -> fp16 convert ----------------
__global__ __launch_bounds__(256) void cvt_f32_f16(const float* __restrict__ s,
                                                   f16* __restrict__ d, int n4) {
  int idx = blockIdx.x * 256 + threadIdx.x;
  if (idx >= n4) return;
  f32x4 v = ((const f32x4*)s)[idx];
  f16x4 o;
#pragma unroll
  for (int q = 0; q < 4; ++q) o[q] = (f16)v[q];
  ((f16x4*)d)[idx] = o;
}

// ---------------- K0b: QKV GEMM  C[r][c] = sum_k hh[r][k]*wh[c][k] ----------
__global__ __launch_bounds__(256) void qkv_gemm(const f16* __restrict__ A, const f16* __restrict__ W,
                                                f16* __restrict__ Qs, f16* __restrict__ Ks,
                                                f16* __restrict__ Vt) {
  __shared__ f16 As[128 * 32];
  __shared__ f16 Bs[128 * 32];
  const int bid = blockIdx.x;
  const int r0 = (bid & 31) << 7;
  const int c0 = (bid >> 5) << 7;
  const int t = threadIdx.x;
  const int lane = t & 63, w = t >> 6;
  const int wr = (w >> 1) << 6, wc = (w & 1) << 6;
  const int l15 = lane & 15, lhi = lane >> 4;

  f32x4 acc[4][4] = {};

  const f16* ga = A + (size_t)(r0 + (t >> 2)) * DM + ((t & 3) << 3);
  const f16* gb = W + (size_t)(c0 + (t >> 2)) * DM + ((t & 3) << 3);
  char* la = (char*)As + w * 1024;
  char* lb = (char*)Bs + w * 1024;

  for (int k0 = 0; k0 < DM; k0 += 32) {
    __syncthreads();
    gload_lds16(ga + k0, la);
    gload_lds16(ga + k0 + (size_t)64 * DM, la + 4096);
    gload_lds16(gb + k0, lb);
    gload_lds16(gb + k0 + (size_t)64 * DM, lb + 4096);
    __syncthreads();
    f16x8 af[4], bf[4];
#pragma unroll
    for (int m = 0; m < 4; ++m)
      af[m] = *(const f16x8*)&As[(wr + m * 16 + l15) * 32 + lhi * 8];
#pragma unroll
    for (int n = 0; n < 4; ++n)
      bf[n] = *(const f16x8*)&Bs[(wc + n * 16 + l15) * 32 + lhi * 8];
#pragma unroll
    for (int m = 0; m < 4; ++m)
#pragma unroll
      for (int n = 0; n < 4; ++n)
        acc[m][n] = mfma16(af[m], bf[n], acc[m][n]);
  }

  const int part = c0 >> 10;  // uniform per block
#pragma unroll
  for (int m = 0; m < 4; ++m) {
#pragma unroll
    for (int n = 0; n < 4; ++n) {
#pragma unroll
      for (int q = 0; q < 4; ++q) {
        int r = r0 + wr + m * 16 + lhi * 4 + q;
        int c = c0 + wc + n * 16 + l15;
        int i = r >> 1, b = r & 1;
        int nh = (c >> 6) & 15, d = c & 63;
        int bn = b * 16 + nh;
        f16 v = (f16)acc[m][n][q];
        if (part == 0)       Qs[((size_t)bn * QLEN + i) * DH + d] = v;
        else if (part == 1)  Ks[((size_t)bn * QLEN + i) * DH + d] = v;
        else                 Vt[((size_t)bn * DH + d) * QLEN + i] = v;
      }
    }
  }
}

// ---------------- K1: flash attention -> attn_vec + row stats ----------------
__global__ __launch_bounds__(256) void flash_attn(const f16* __restrict__ Qs, const f16* __restrict__ Ks,
                                                  const f16* __restrict__ Vt, float* __restrict__ av,
                                                  float* __restrict__ sm, float* __restrict__ srl) {
  __shared__ f16 plds[4][16 * 32];
  const int bid = blockIdx.x;
  const int bn = bid >> 4, ib = bid & 15;
  const int t = threadIdx.x, lane = t & 63, w = t >> 6;
  const int l15 = lane & 15, lhi = lane >> 4;
  const int i0 = (ib << 7) + (w << 5);
  const f16* Qb = Qs + ((size_t)bn << 17);
  const f16* Kb = Ks + ((size_t)bn << 17);
  const f16* Vb = Vt + ((size_t)bn << 17);
  f16* pw = plds[w];

  f16x8 qf[2][2];
#pragma unroll
  for (int rg = 0; rg < 2; ++rg)
#pragma unroll
    for (int kc = 0; kc < 2; ++kc)
      qf[rg][kc] = *(const f16x8*)&Qb[(size_t)(i0 + rg * 16 + l15) * DH + kc * 32 + lhi * 8];

  f32x4 o[2][4] = {};
  float mrun[2][4], lrun[2][4];
#pragma unroll
  for (int rg = 0; rg < 2; ++rg)
#pragma unroll
    for (int q = 0; q < 4; ++q) { mrun[rg][q] = -1e30f; lrun[rg][q] = 0.f; }

  for (int j0 = 0; j0 < QLEN; j0 += 32) {
    f16x8 kf[2][2], vf[4];
#pragma unroll
    for (int jc = 0; jc < 2; ++jc)
#pragma unroll
      for (int kc = 0; kc < 2; ++kc)
        kf[jc][kc] = *(const f16x8*)&Kb[(size_t)(j0 + jc * 16 + l15) * DH + kc * 32 + lhi * 8];
#pragma unroll
    for (int dc = 0; dc < 4; ++dc)
      vf[dc] = *(const f16x8*)&Vb[(size_t)(dc * 16 + l15) * QLEN + j0 + lhi * 8];

#pragma unroll
    for (int rg = 0; rg < 2; ++rg) {
      f32x4 s[2];
#pragma unroll
      for (int jc = 0; jc < 2; ++jc) {
        f32x4 z = {0.f, 0.f, 0.f, 0.f};
        z = mfma16(qf[rg][0], kf[jc][0], z);
        z = mfma16(qf[rg][1], kf[jc][1], z);
        s[jc] = z;
      }
      float p[2][4], alpha[4];
#pragma unroll
      for (int q = 0; q < 4; ++q) {
        float v0 = s[0][q] * SCALE, v1 = s[1][q] * SCALE;
        float tm = fmaxf(v0, v1);
        tm = fmaxf(tm, __shfl_xor(tm, 1));
        tm = fmaxf(tm, __shfl_xor(tm, 2));
        tm = fmaxf(tm, __shfl_xor(tm, 4));
        tm = fmaxf(tm, __shfl_xor(tm, 8));
        float mnew = fmaxf(mrun[rg][q], tm);
        alpha[q] = __expf(mrun[rg][q] - mnew);
        mrun[rg][q] = mnew;
        p[0][q] = __expf(v0 - mnew);
        p[1][q] = __expf(v1 - mnew);
        float r = p[0][q] + p[1][q];
        r += __shfl_xor(r, 1);
        r += __shfl_xor(r, 2);
        r += __shfl_xor(r, 4);
        r += __shfl_xor(r, 8);
        lrun[rg][q] = lrun[rg][q] * alpha[q] + r;
      }
#pragma unroll
      for (int dc = 0; dc < 4; ++dc)
#pragma unroll
        for (int q = 0; q < 4; ++q)
          o[rg][dc][q] *= alpha[q];
#pragma unroll
      for (int jc = 0; jc < 2; ++jc)
#pragma unroll
        for (int q = 0; q < 4; ++q)
          pw[(lhi * 4 + q) * 32 + jc * 16 + l15] = (f16)p[jc][q];
      f16x8 pa = *(const f16x8*)&pw[l15 * 32 + lhi * 8];
#pragma unroll
      for (int dc = 0; dc < 4; ++dc)
        o[rg][dc] = mfma16(pa, vf[dc], o[rg][dc]);
    }
  }

  const int b = bn >> 4, nh = bn & 15;
#pragma unroll
  for (int rg = 0; rg < 2; ++rg)
#pragma unroll
    for (int dc = 0; dc < 4; ++dc)
#pragma unroll
      for (int q = 0; q < 4; ++q) {
        int i = i0 + rg * 16 + lhi * 4 + q;
        av[((size_t)i * BSZ + b) * (NH * DH) + nh * DH + dc * 16 + l15] =
            o[rg][dc][q] / lrun[rg][q];
      }
  if (l15 == 0) {
#pragma unroll
    for (int rg = 0; rg < 2; ++rg)
#pragma unroll
      for (int q = 0; q < 4; ++q) {
        int i = i0 + rg * 16 + lhi * 4 + q;
        sm[bn * QLEN + i] = mrun[rg][q];
        srl[bn * QLEN + i] = 1.0f / lrun[rg][q];
      }
  }
}

// ---------------- K2: materialize attn_prob [i][j][b][n] ----------------
// R6 structure; R10 change: per-chunk barrier is barrier_lds() (lgkmcnt-only),
// so nt stores are never drained at barriers -- they stay in flight across
// chunks (vmcnt hardware cap ~63 = natural throttle, ~4 chunks deep).
__global__ __launch_bounds__(256, 2) void write_probs(const f16* __restrict__ Qs, const f16* __restrict__ Ks,
                                                      const float* __restrict__ sm, const float* __restrict__ srl,
                                                      float* __restrict__ pout) {
  __shared__ f16 tile[2][16 * 32 * 32];  // 2 x 32 KiB
  const int bid = blockIdx.x;            // 1024 blocks
  const int it = bid >> 3, jt = bid & 7; // jt%8 -> XCD-local K panel
  const int i0 = it << 4, j0 = jt << 8;
  const int t = threadIdx.x, lane = t & 63, w = t >> 6;
  const int l15 = lane & 15, lhi = lane >> 4;

  // persistent row stats for this wave's 8 bn (broadcast loads)
  float mm[8][4], rl[8][4];
#pragma unroll
  for (int bl = 0; bl < 8; ++bl) {
    const int bn = w * 8 + bl;
#pragma unroll
    for (int q = 0; q < 4; ++q) {
      const int i = i0 + lhi * 4 + q;
      mm[bl][q] = sm[bn * QLEN + i];
      rl[bl][q] = srl[bn * QLEN + i];
    }
  }

  // store-phase lane mapping (constant across chunks)
  const int o = t & 3;             // bn octet 0..3
  const int jl_s = (t >> 2) & 31;  // j within chunk
  const int ihalf = t >> 7;        // i parity
  const int quad = o ^ ((jl_s & 7) >> 1);
  const bool hsw = (jl_s & 1);

  for (int ch = 0; ch < 8; ++ch) {
    f16* tb = tile[ch & 1];
    const int jbase = j0 + ch * 32;

    f16 stv[8][2][4];
#pragma unroll
    for (int bl = 0; bl < 8; ++bl) {
      const int bn = w * 8 + bl;
      const f16* Qb = Qs + ((size_t)bn << 17);
      const f16* Kb = Ks + ((size_t)bn << 17);
      f16x8 qf[2], kf[2][2];
#pragma unroll
      for (int kc = 0; kc < 2; ++kc)
        qf[kc] = *(const f16x8*)&Qb[(size_t)(i0 + l15) * DH + kc * 32 + lhi * 8];
#pragma unroll
      for (int jc = 0; jc < 2; ++jc)
#pragma unroll
        for (int kc = 0; kc < 2; ++kc)
          kf[jc][kc] = *(const f16x8*)&Kb[(size_t)(jbase + jc * 16 + l15) * DH + kc * 32 + lhi * 8];
#pragma unroll
      for (int jc = 0; jc < 2; ++jc) {
        f32x4 z = {0.f, 0.f, 0.f, 0.f};
        z = mfma16(qf[0], kf[jc][0], z);
        z = mfma16(qf[1], kf[jc][1], z);
#pragma unroll
        for (int q = 0; q < 4; ++q)
          stv[bl][jc][q] = (f16)(__expf(z[q] * SCALE - mm[bl][q]) * rl[bl][q]);
      }
    }

    // deposit: 16 x ds_write_b64; granule g = bn>>2 at position g ^ (jl&7)
#pragma unroll
    for (int h = 0; h < 2; ++h) {
      const int g = w * 2 + h;
#pragma unroll
      for (int jc = 0; jc < 2; ++jc)
#pragma unroll
        for (int q = 0; q < 4; ++q) {
          const int i_l = lhi * 4 + q;
          const int jl = jc * 16 + l15;
          f16x4 v = {stv[4 * h + 0][jc][q], stv[4 * h + 1][jc][q],
                     stv[4 * h + 2][jc][q], stv[4 * h + 3][jc][q]};
          *(f16x4*)&tb[(i_l * 32 + jl) * 32 + ((g ^ (jl & 7)) << 2)] = v;
        }
    }
    barrier_lds();  // deposit visible to all waves; nt stores NOT drained

    // store: 8 passes; 4 lanes complete each 128B line; nt stores stay
    // in flight across chunks (double buffer; barrier placement proof
    // unchanged: a wave re-depositing buffer b must pass the barrier that
    // all waves reached only after finishing their reads of b)
#pragma unroll
    for (int p = 0; p < 8; ++p) {
      const int i_l = p * 2 + ihalf;
      f16x8 v = *(const f16x8*)&tb[(i_l * 32 + jl_s) * 32 + (quad << 3)];
      f16x4 vl = {v[0], v[1], v[2], v[3]};
      f16x4 vh = {v[4], v[5], v[6], v[7]};
      f16x4 fa = hsw ? vh : vl;
      f16x4 fb = hsw ? vl : vh;
      f32x4 lo = {(float)fa[0], (float)fa[1], (float)fa[2], (float)fa[3]};
      f32x4 hi = {(float)fb[0], (float)fb[1], (float)fb[2], (float)fb[3]};
      float* op = pout + ((size_t)(i0 + i_l) * QLEN + jbase + jl_s) * NBN + o * 8;
      __builtin_nontemporal_store(lo, (f32x4*)op);
      __builtin_nontemporal_store(hi, (f32x4*)(op + 4));
    }
  }
}

// ---------------- launcher ----------------
extern "C" void kernel_launch(void* const* d_in, const int* in_sizes, int n_in,
                              void* d_out, int out_size, void* d_ws, size_t ws_size,
                              hipStream_t stream) {
  const float* h  = (const float*)d_in[0];
  const float* wq = (const float*)d_in[1];
  float* av   = (float*)d_out;
  float* pout = av + (size_t)QLEN * BSZ * NH * DH;

  char* ws = (char*)d_ws;
  f16* hh  = (f16*)ws;                        // 8 MiB
  f16* wh  = (f16*)(ws + (8u << 20));         // 6 MiB
  f16* Qsc = (f16*)(ws + (16u << 20));        // 8 MiB
  f16* Ksc = (f16*)(ws + (24u << 20));        // 8 MiB
  f16* Vtc = (f16*)(ws + (32u << 20));        // 8 MiB
  float* smv  = (float*)(ws + (40u << 20));
  float* srlv = (float*)(ws + (40u << 20) + (QLEN * NBN * 4));

  const int nh4 = QLEN * BSZ * DM / 4;
  const int nw4 = 3 * NH * DH * DM / 4;
  cvt_f32_f16<<<nh4 / 256, 256, 0, stream>>>(h, hh, nh4);
  cvt_f32_f16<<<nw4 / 256, 256, 0, stream>>>(wq, wh, nw4);
  qkv_gemm<<<32 * 24, 256, 0, stream>>>(hh, wh, Qsc, Ksc, Vtc);
  flash_attn<<<NBN * 16, 256, 0, stream>>>(Qsc, Ksc, Vtc, av, smv, srlv);
  write_probs<<<128 * 8, 256, 0, stream>>>(Qsc, Ksc, smv, srlv, pout);
}

// Round 11
// 373.426 us; speedup vs baseline: 1.1584x; 1.0376x over previous
//
#include <hip/hip_runtime.h>

typedef _Float16 f16;
typedef f16 f16x8 __attribute__((ext_vector_type(8)));
typedef f16 f16x4 __attribute__((ext_vector_type(4)));
typedef float f32x4 __attribute__((ext_vector_type(4)));

#define QLEN 2048
#define BSZ 2
#define NH 16
#define DH 64
#define DM 1024
#define NBN (BSZ*NH)
#define SCALE 0.125f

static __device__ __forceinline__ f32x4 mfma16(f16x8 a, f16x8 b, f32x4 c) {
  return __builtin_amdgcn_mfma_f32_16x16x32_f16(a, b, c, 0, 0, 0);
}

// async global->LDS, 16B per lane; lds dest = wave-uniform base + lane*16
static __device__ __forceinline__ void gload_lds16(const void* g, void* l) {
  __builtin_amdgcn_global_load_lds((const __attribute__((address_space(1))) unsigned int*)g,
                                   (__attribute__((address_space(3))) unsigned int*)l,
                                   16, 0, 0);
}

// LDS-only barrier: waits ds ops (lgkmcnt) but does NOT drain global stores.
static __device__ __forceinline__ void barrier_lds() {
  __builtin_amdgcn_sched_barrier(0);
  asm volatile("s_waitcnt lgkmcnt(0)" ::: "memory");
  __builtin_amdgcn_s_barrier();
  __builtin_amdgcn_sched_barrier(0);
}

// ---------------- K0a: fp32 -> fp16 convert ----------------
__global__ __launch_bounds__(256) void cvt_f32_f16(const float* __restrict__ s,
                                                   f16* __restrict__ d, int n4) {
  int idx = blockIdx.x * 256 + threadIdx.x;
  if (idx >= n4) return;
  f32x4 v = ((const f32x4*)s)[idx];
  f16x4 o;
#pragma unroll
  for (int q = 0; q < 4; ++q) o[q] = (f16)v[q];
  ((f16x4*)d)[idx] = o;
}

// ---------------- K0b: QKV GEMM (R6-exact) ----------------
__global__ __launch_bounds__(256) void qkv_gemm(const f16* __restrict__ A, const f16* __restrict__ W,
                                                f16* __restrict__ Qs, f16* __restrict__ Ks,
                                                f16* __restrict__ Vt) {
  __shared__ f16 As[128 * 32];
  __shared__ f16 Bs[128 * 32];
  const int bid = blockIdx.x;
  const int r0 = (bid & 31) << 7;
  const int c0 = (bid >> 5) << 7;
  const int t = threadIdx.x;
  const int lane = t & 63, w = t >> 6;
  const int wr = (w >> 1) << 6, wc = (w & 1) << 6;
  const int l15 = lane & 15, lhi = lane >> 4;

  f32x4 acc[4][4] = {};

  const f16* ga = A + (size_t)(r0 + (t >> 2)) * DM + ((t & 3) << 3);
  const f16* gb = W + (size_t)(c0 + (t >> 2)) * DM + ((t & 3) << 3);
  char* la = (char*)As + w * 1024;
  char* lb = (char*)Bs + w * 1024;

  for (int k0 = 0; k0 < DM; k0 += 32) {
    __syncthreads();
    gload_lds16(ga + k0, la);
    gload_lds16(ga + k0 + (size_t)64 * DM, la + 4096);
    gload_lds16(gb + k0, lb);
    gload_lds16(gb + k0 + (size_t)64 * DM, lb + 4096);
    __syncthreads();
    f16x8 af[4], bf[4];
#pragma unroll
    for (int m = 0; m < 4; ++m)
      af[m] = *(const f16x8*)&As[(wr + m * 16 + l15) * 32 + lhi * 8];
#pragma unroll
    for (int n = 0; n < 4; ++n)
      bf[n] = *(const f16x8*)&Bs[(wc + n * 16 + l15) * 32 + lhi * 8];
#pragma unroll
    for (int m = 0; m < 4; ++m)
#pragma unroll
      for (int n = 0; n < 4; ++n)
        acc[m][n] = mfma16(af[m], bf[n], acc[m][n]);
  }

  const int part = c0 >> 10;  // uniform per block
#pragma unroll
  for (int m = 0; m < 4; ++m) {
#pragma unroll
    for (int n = 0; n < 4; ++n) {
#pragma unroll
      for (int q = 0; q < 4; ++q) {
        int r = r0 + wr + m * 16 + lhi * 4 + q;
        int c = c0 + wc + n * 16 + l15;
        int i = r >> 1, b = r & 1;
        int nh = (c >> 6) & 15, d = c & 63;
        int bn = b * 16 + nh;
        f16 v = (f16)acc[m][n][q];
        if (part == 0)       Qs[((size_t)bn * QLEN + i) * DH + d] = v;
        else if (part == 1)  Ks[((size_t)bn * QLEN + i) * DH + d] = v;
        else                 Vt[((size_t)bn * DH + d) * QLEN + i] = v;
      }
    }
  }
}

// ---------------- K1: flash attention (R6-exact) ----------------
__global__ __launch_bounds__(256) void flash_attn(const f16* __restrict__ Qs, const f16* __restrict__ Ks,
                                                  const f16* __restrict__ Vt, float* __restrict__ av,
                                                  float* __restrict__ sm, float* __restrict__ srl) {
  __shared__ f16 plds[4][16 * 32];
  const int bid = blockIdx.x;
  const int bn = bid >> 4, ib = bid & 15;
  const int t = threadIdx.x, lane = t & 63, w = t >> 6;
  const int l15 = lane & 15, lhi = lane >> 4;
  const int i0 = (ib << 7) + (w << 5);
  const f16* Qb = Qs + ((size_t)bn << 17);
  const f16* Kb = Ks + ((size_t)bn << 17);
  const f16* Vb = Vt + ((size_t)bn << 17);
  f16* pw = plds[w];

  f16x8 qf[2][2];
#pragma unroll
  for (int rg = 0; rg < 2; ++rg)
#pragma unroll
    for (int kc = 0; kc < 2; ++kc)
      qf[rg][kc] = *(const f16x8*)&Qb[(size_t)(i0 + rg * 16 + l15) * DH + kc * 32 + lhi * 8];

  f32x4 o[2][4] = {};
  float mrun[2][4], lrun[2][4];
#pragma unroll
  for (int rg = 0; rg < 2; ++rg)
#pragma unroll
    for (int q = 0; q < 4; ++q) { mrun[rg][q] = -1e30f; lrun[rg][q] = 0.f; }

  for (int j0 = 0; j0 < QLEN; j0 += 32) {
    f16x8 kf[2][2], vf[4];
#pragma unroll
    for (int jc = 0; jc < 2; ++jc)
#pragma unroll
      for (int kc = 0; kc < 2; ++kc)
        kf[jc][kc] = *(const f16x8*)&Kb[(size_t)(j0 + jc * 16 + l15) * DH + kc * 32 + lhi * 8];
#pragma unroll
    for (int dc = 0; dc < 4; ++dc)
      vf[dc] = *(const f16x8*)&Vb[(size_t)(dc * 16 + l15) * QLEN + j0 + lhi * 8];

#pragma unroll
    for (int rg = 0; rg < 2; ++rg) {
      f32x4 s[2];
#pragma unroll
      for (int jc = 0; jc < 2; ++jc) {
        f32x4 z = {0.f, 0.f, 0.f, 0.f};
        z = mfma16(qf[rg][0], kf[jc][0], z);
        z = mfma16(qf[rg][1], kf[jc][1], z);
        s[jc] = z;
      }
      float p[2][4], alpha[4];
#pragma unroll
      for (int q = 0; q < 4; ++q) {
        float v0 = s[0][q] * SCALE, v1 = s[1][q] * SCALE;
        float tm = fmaxf(v0, v1);
        tm = fmaxf(tm, __shfl_xor(tm, 1));
        tm = fmaxf(tm, __shfl_xor(tm, 2));
        tm = fmaxf(tm, __shfl_xor(tm, 4));
        tm = fmaxf(tm, __shfl_xor(tm, 8));
        float mnew = fmaxf(mrun[rg][q], tm);
        alpha[q] = __expf(mrun[rg][q] - mnew);
        mrun[rg][q] = mnew;
        p[0][q] = __expf(v0 - mnew);
        p[1][q] = __expf(v1 - mnew);
        float r = p[0][q] + p[1][q];
        r += __shfl_xor(r, 1);
        r += __shfl_xor(r, 2);
        r += __shfl_xor(r, 4);
        r += __shfl_xor(r, 8);
        lrun[rg][q] = lrun[rg][q] * alpha[q] + r;
      }
#pragma unroll
      for (int dc = 0; dc < 4; ++dc)
#pragma unroll
        for (int q = 0; q < 4; ++q)
          o[rg][dc][q] *= alpha[q];
#pragma unroll
      for (int jc = 0; jc < 2; ++jc)
#pragma unroll
        for (int q = 0; q < 4; ++q)
          pw[(lhi * 4 + q) * 32 + jc * 16 + l15] = (f16)p[jc][q];
      f16x8 pa = *(const f16x8*)&pw[l15 * 32 + lhi * 8];
#pragma unroll
      for (int dc = 0; dc < 4; ++dc)
        o[rg][dc] = mfma16(pa, vf[dc], o[rg][dc]);
    }
  }

  const int b = bn >> 4, nh = bn & 15;
#pragma unroll
  for (int rg = 0; rg < 2; ++rg)
#pragma unroll
    for (int dc = 0; dc < 4; ++dc)
#pragma unroll
      for (int q = 0; q < 4; ++q) {
        int i = i0 + rg * 16 + lhi * 4 + q;
        av[((size_t)i * BSZ + b) * (NH * DH) + nh * DH + dc * 16 + l15] =
            o[rg][dc][q] / lrun[rg][q];
      }
  if (l15 == 0) {
#pragma unroll
    for (int rg = 0; rg < 2; ++rg)
#pragma unroll
      for (int q = 0; q < 4; ++q) {
        int i = i0 + rg * 16 + lhi * 4 + q;
        sm[bn * QLEN + i] = mrun[rg][q];
        srl[bn * QLEN + i] = 1.0f / lrun[rg][q];
      }
  }
}

// ---------------- K2: materialize attn_prob [i][j][b][n] ----------------
// R11: vmcnt-FIFO pipeline. 512 threads / 8 waves x 4 bn. 16-j chunks.
// Per chunk: [compute from prefetched K] [issue next K loads] [deposit,
// lgkm-only barrier] [plain stores]. Stores are always the NEWEST vmem ops,
// so the next chunk's load-wait (vmcnt(#stores)) never drains them -- each
// chunk's stores get a full chunk-period to retire. Q frags + stats hoisted.
#define LOADK(buf, chn)                                                        \
  do {                                                                         \
    _Pragma("unroll") for (int bl_ = 0; bl_ < 4; ++bl_) {                      \
      const f16* Kb_ = Ks + (((size_t)(w4 + bl_)) << 17) +                     \
                       (size_t)(j0 + (chn) * 16 + l15) * DH + lhi * 8;         \
      buf[bl_][0] = *(const f16x8*)(Kb_);                                      \
      buf[bl_][1] = *(const f16x8*)(Kb_ + 32);                                 \
    }                                                                          \
  } while (0)

#define CHUNK(cur, nxt, ch)                                                    \
  do {                                                                         \
    const int jbase_ = j0 + (ch) * 16;                                         \
    f16 stv[4][4];                                                             \
    _Pragma("unroll") for (int bl_ = 0; bl_ < 4; ++bl_) {                      \
      f32x4 z = {0.f, 0.f, 0.f, 0.f};                                          \
      z = mfma16(qf[bl_][0], cur[bl_][0], z);                                  \
      z = mfma16(qf[bl_][1], cur[bl_][1], z);                                  \
      _Pragma("unroll") for (int q_ = 0; q_ < 4; ++q_)                         \
        stv[bl_][q_] = (f16)(__expf(z[q_] * SCALE - mm[bl_][q_]) * rl[bl_][q_]); \
    }                                                                          \
    __builtin_amdgcn_sched_barrier(0);                                         \
    { const int nch_ = ((ch) + 1 < 16) ? (ch) + 1 : 15; LOADK(nxt, nch_); }    \
    __builtin_amdgcn_sched_barrier(0);                                         \
    f16* tb_ = tile[(ch) & 1];                                                 \
    _Pragma("unroll") for (int q_ = 0; q_ < 4; ++q_) {                         \
      const int i_l = lhi * 4 + q_;                                            \
      const int jl = l15;                                                      \
      f16x4 v = {stv[0][q_], stv[1][q_], stv[2][q_], stv[3][q_]};              \
      *(f16x4*)&tb_[(i_l * 16 + jl) * 32 + ((w ^ (jl & 7)) << 2)] = v;         \
    }                                                                          \
    barrier_lds();                                                             \
    _Pragma("unroll") for (int p_ = 0; p_ < 2; ++p_) {                         \
      const int i_l = p_ * 8 + w;                                              \
      f16x8 v = *(const f16x8*)&tb_[(i_l * 16 + jl_s) * 32 + (quad << 3)];     \
      f16x4 vl = {v[0], v[1], v[2], v[3]};                                     \
      f16x4 vh = {v[4], v[5], v[6], v[7]};                                     \
      f16x4 fa = hsw ? vh : vl;                                                \
      f16x4 fb = hsw ? vl : vh;                                                \
      f32x4 lo = {(float)fa[0], (float)fa[1], (float)fa[2], (float)fa[3]};     \
      f32x4 hi = {(float)fb[0], (float)fb[1], (float)fb[2], (float)fb[3]};     \
      float* op = pout + ((size_t)(i0 + i_l) * QLEN + jbase_ + jl_s) * NBN + o * 8; \
      *(f32x4*)op = lo;                                                        \
      *(f32x4*)(op + 4) = hi;                                                  \
    }                                                                          \
  } while (0)

__global__ __launch_bounds__(512, 1) void write_probs(const f16* __restrict__ Qs, const f16* __restrict__ Ks,
                                                      const float* __restrict__ sm, const float* __restrict__ srl,
                                                      float* __restrict__ pout) {
  __shared__ f16 tile[2][16 * 16 * 32];  // 2 x 16 KiB
  const int bid = blockIdx.x;            // 1024 blocks
  const int it = bid >> 3, jt = bid & 7; // jt%8 -> XCD-local K panel
  const int i0 = it << 4, j0 = jt << 8;
  const int t = threadIdx.x, lane = t & 63, w = t >> 6;  // 8 waves, 4 bn each
  const int l15 = lane & 15, lhi = lane >> 4;
  const int w4 = w * 4;

  // hoisted per-block state: Q frags + row stats for this wave's 4 bn
  f16x8 qf[4][2];
  float mm[4][4], rl[4][4];
#pragma unroll
  for (int bl = 0; bl < 4; ++bl) {
    const int bn = w4 + bl;
    const f16* Qb = Qs + ((size_t)bn << 17);
#pragma unroll
    for (int kc = 0; kc < 2; ++kc)
      qf[bl][kc] = *(const f16x8*)&Qb[(size_t)(i0 + l15) * DH + kc * 32 + lhi * 8];
#pragma unroll
    for (int q = 0; q < 4; ++q) {
      const int i = i0 + lhi * 4 + q;
      mm[bl][q] = sm[bn * QLEN + i];
      rl[bl][q] = srl[bn * QLEN + i];
    }
  }

  // store-phase lane mapping (constant across chunks)
  const int o = t & 3;             // bn octet 0..3 (32B of each 128B line)
  const int jl_s = (t >> 2) & 15;  // j within chunk
  const int quad = o ^ ((jl_s & 7) >> 1);
  const bool hsw = (jl_s & 1);

  f16x8 kfA[4][2], kfB[4][2];
  LOADK(kfA, 0);

  for (int ch = 0; ch < 16; ch += 2) {
    CHUNK(kfA, kfB, ch);
    CHUNK(kfB, kfA, ch + 1);
  }
}

// ---------------- launcher ----------------
extern "C" void kernel_launch(void* const* d_in, const int* in_sizes, int n_in,
                              void* d_out, int out_size, void* d_ws, size_t ws_size,
                              hipStream_t stream) {
  const float* h  = (const float*)d_in[0];
  const float* wq = (const float*)d_in[1];
  float* av   = (float*)d_out;
  float* pout = av + (size_t)QLEN * BSZ * NH * DH;

  char* ws = (char*)d_ws;
  f16* hh  = (f16*)ws;                        // 8 MiB
  f16* wh  = (f16*)(ws + (8u << 20));         // 6 MiB
  f16* Qsc = (f16*)(ws + (16u << 20));        // 8 MiB
  f16* Ksc = (f16*)(ws + (24u << 20));        // 8 MiB
  f16* Vtc = (f16*)(ws + (32u << 20));        // 8 MiB
  float* smv  = (float*)(ws + (40u << 20));
  float* srlv = (float*)(ws + (40u << 20) + (QLEN * NBN * 4));

  const int nh4 = QLEN * BSZ * DM / 4;
  const int nw4 = 3 * NH * DH * DM / 4;
  cvt_f32_f16<<<nh4 / 256, 256, 0, stream>>>(h, hh, nh4);
  cvt_f32_f16<<<nw4 / 256, 256, 0, stream>>>(wq, wh, nw4);
  qkv_gemm<<<32 * 24, 256, 0, stream>>>(hh, wh, Qsc, Ksc, Vtc);
  flash_attn<<<NBN * 16, 256, 0, stream>>>(Qsc, Ksc, Vtc, av, smv, srlv);
  write_probs<<<128 * 8, 512, 0, stream>>>(Qsc, Ksc, smv, srlv, pout);
}

// Round 12
// 360.733 us; speedup vs baseline: 1.1991x; 1.0352x over previous
//
#include <hip/hip_runtime.h>

typedef _Float16 f16;
typedef f16 f16x8 __attribute__((ext_vector_type(8)));
typedef f16 f16x4 __attribute__((ext_vector_type(4)));
typedef float f32x4 __attribute__((ext_vector_type(4)));

#define QLEN 2048
#define BSZ 2
#define NH 16
#define DH 64
#define DM 1024
#define NBN (BSZ*NH)
#define SCALE 0.125f

static __device__ __forceinline__ f32x4 mfma16(f16x8 a, f16x8 b, f32x4 c) {
  return __builtin_amdgcn_mfma_f32_16x16x32_f16(a, b, c, 0, 0, 0);
}

// async global->LDS, 16B per lane; lds dest = wave-uniform base + lane*16
static __device__ __forceinline__ void gload_lds16(const void* g, void* l) {
  __builtin_amdgcn_global_load_lds((const __attribute__((address_space(1))) unsigned int*)g,
                                   (__attribute__((address_space(3))) unsigned int*)l,
                                   16, 0, 0);
}

// LDS-only barrier: waits ds ops (lgkmcnt) but does NOT drain global stores.
static __device__ __forceinline__ void barrier_lds() {
  __builtin_amdgcn_sched_barrier(0);
  asm volatile("s_waitcnt lgkmcnt(0)" ::: "memory");
  __builtin_amdgcn_s_barrier();
  __builtin_amdgcn_sched_barrier(0);
}

// ---------------- K0a: fp32 -> fp16 convert ----------------
__global__ __launch_bounds__(256) void cvt_f32_f16(const float* __restrict__ s,
                                                   f16* __restrict__ d, int n4) {
  int idx = blockIdx.x * 256 + threadIdx.x;
  if (idx >= n4) return;
  f32x4 v = ((const f32x4*)s)[idx];
  f16x4 o;
#pragma unroll
  for (int q = 0; q < 4; ++q) o[q] = (f16)v[q];
  ((f16x4*)d)[idx] = o;
}

// ---------------- K0b: QKV GEMM (R6-exact) ----------------
__global__ __launch_bounds__(256) void qkv_gemm(const f16* __restrict__ A, const f16* __restrict__ W,
                                                f16* __restrict__ Qs, f16* __restrict__ Ks,
                                                f16* __restrict__ Vt) {
  __shared__ f16 As[128 * 32];
  __shared__ f16 Bs[128 * 32];
  const int bid = blockIdx.x;
  const int r0 = (bid & 31) << 7;
  const int c0 = (bid >> 5) << 7;
  const int t = threadIdx.x;
  const int lane = t & 63, w = t >> 6;
  const int wr = (w >> 1) << 6, wc = (w & 1) << 6;
  const int l15 = lane & 15, lhi = lane >> 4;

  f32x4 acc[4][4] = {};

  const f16* ga = A + (size_t)(r0 + (t >> 2)) * DM + ((t & 3) << 3);
  const f16* gb = W + (size_t)(c0 + (t >> 2)) * DM + ((t & 3) << 3);
  char* la = (char*)As + w * 1024;
  char* lb = (char*)Bs + w * 1024;

  for (int k0 = 0; k0 < DM; k0 += 32) {
    __syncthreads();
    gload_lds16(ga + k0, la);
    gload_lds16(ga + k0 + (size_t)64 * DM, la + 4096);
    gload_lds16(gb + k0, lb);
    gload_lds16(gb + k0 + (size_t)64 * DM, lb + 4096);
    __syncthreads();
    f16x8 af[4], bf[4];
#pragma unroll
    for (int m = 0; m < 4; ++m)
      af[m] = *(const f16x8*)&As[(wr + m * 16 + l15) * 32 + lhi * 8];
#pragma unroll
    for (int n = 0; n < 4; ++n)
      bf[n] = *(const f16x8*)&Bs[(wc + n * 16 + l15) * 32 + lhi * 8];
#pragma unroll
    for (int m = 0; m < 4; ++m)
#pragma unroll
      for (int n = 0; n < 4; ++n)
        acc[m][n] = mfma16(af[m], bf[n], acc[m][n]);
  }

  const int part = c0 >> 10;  // uniform per block
#pragma unroll
  for (int m = 0; m < 4; ++m) {
#pragma unroll
    for (int n = 0; n < 4; ++n) {
#pragma unroll
      for (int q = 0; q < 4; ++q) {
        int r = r0 + wr + m * 16 + lhi * 4 + q;
        int c = c0 + wc + n * 16 + l15;
        int i = r >> 1, b = r & 1;
        int nh = (c >> 6) & 15, d = c & 63;
        int bn = b * 16 + nh;
        f16 v = (f16)acc[m][n][q];
        if (part == 0)       Qs[((size_t)bn * QLEN + i) * DH + d] = v;
        else if (part == 1)  Ks[((size_t)bn * QLEN + i) * DH + d] = v;
        else                 Vt[((size_t)bn * DH + d) * QLEN + i] = v;
      }
    }
  }
}

// ---------------- K1: flash attention (R6-exact) ----------------
__global__ __launch_bounds__(256) void flash_attn(const f16* __restrict__ Qs, const f16* __restrict__ Ks,
                                                  const f16* __restrict__ Vt, float* __restrict__ av,
                                                  float* __restrict__ sm, float* __restrict__ srl) {
  __shared__ f16 plds[4][16 * 32];
  const int bid = blockIdx.x;
  const int bn = bid >> 4, ib = bid & 15;
  const int t = threadIdx.x, lane = t & 63, w = t >> 6;
  const int l15 = lane & 15, lhi = lane >> 4;
  const int i0 = (ib << 7) + (w << 5);
  const f16* Qb = Qs + ((size_t)bn << 17);
  const f16* Kb = Ks + ((size_t)bn << 17);
  const f16* Vb = Vt + ((size_t)bn << 17);
  f16* pw = plds[w];

  f16x8 qf[2][2];
#pragma unroll
  for (int rg = 0; rg < 2; ++rg)
#pragma unroll
    for (int kc = 0; kc < 2; ++kc)
      qf[rg][kc] = *(const f16x8*)&Qb[(size_t)(i0 + rg * 16 + l15) * DH + kc * 32 + lhi * 8];

  f32x4 o[2][4] = {};
  float mrun[2][4], lrun[2][4];
#pragma unroll
  for (int rg = 0; rg < 2; ++rg)
#pragma unroll
    for (int q = 0; q < 4; ++q) { mrun[rg][q] = -1e30f; lrun[rg][q] = 0.f; }

  for (int j0 = 0; j0 < QLEN; j0 += 32) {
    f16x8 kf[2][2], vf[4];
#pragma unroll
    for (int jc = 0; jc < 2; ++jc)
#pragma unroll
      for (int kc = 0; kc < 2; ++kc)
        kf[jc][kc] = *(const f16x8*)&Kb[(size_t)(j0 + jc * 16 + l15) * DH + kc * 32 + lhi * 8];
#pragma unroll
    for (int dc = 0; dc < 4; ++dc)
      vf[dc] = *(const f16x8*)&Vb[(size_t)(dc * 16 + l15) * QLEN + j0 + lhi * 8];

#pragma unroll
    for (int rg = 0; rg < 2; ++rg) {
      f32x4 s[2];
#pragma unroll
      for (int jc = 0; jc < 2; ++jc) {
        f32x4 z = {0.f, 0.f, 0.f, 0.f};
        z = mfma16(qf[rg][0], kf[jc][0], z);
        z = mfma16(qf[rg][1], kf[jc][1], z);
        s[jc] = z;
      }
      float p[2][4], alpha[4];
#pragma unroll
      for (int q = 0; q < 4; ++q) {
        float v0 = s[0][q] * SCALE, v1 = s[1][q] * SCALE;
        float tm = fmaxf(v0, v1);
        tm = fmaxf(tm, __shfl_xor(tm, 1));
        tm = fmaxf(tm, __shfl_xor(tm, 2));
        tm = fmaxf(tm, __shfl_xor(tm, 4));
        tm = fmaxf(tm, __shfl_xor(tm, 8));
        float mnew = fmaxf(mrun[rg][q], tm);
        alpha[q] = __expf(mrun[rg][q] - mnew);
        mrun[rg][q] = mnew;
        p[0][q] = __expf(v0 - mnew);
        p[1][q] = __expf(v1 - mnew);
        float r = p[0][q] + p[1][q];
        r += __shfl_xor(r, 1);
        r += __shfl_xor(r, 2);
        r += __shfl_xor(r, 4);
        r += __shfl_xor(r, 8);
        lrun[rg][q] = lrun[rg][q] * alpha[q] + r;
      }
#pragma unroll
      for (int dc = 0; dc < 4; ++dc)
#pragma unroll
        for (int q = 0; q < 4; ++q)
          o[rg][dc][q] *= alpha[q];
#pragma unroll
      for (int jc = 0; jc < 2; ++jc)
#pragma unroll
        for (int q = 0; q < 4; ++q)
          pw[(lhi * 4 + q) * 32 + jc * 16 + l15] = (f16)p[jc][q];
      f16x8 pa = *(const f16x8*)&pw[l15 * 32 + lhi * 8];
#pragma unroll
      for (int dc = 0; dc < 4; ++dc)
        o[rg][dc] = mfma16(pa, vf[dc], o[rg][dc]);
    }
  }

  const int b = bn >> 4, nh = bn & 15;
#pragma unroll
  for (int rg = 0; rg < 2; ++rg)
#pragma unroll
    for (int dc = 0; dc < 4; ++dc)
#pragma unroll
      for (int q = 0; q < 4; ++q) {
        int i = i0 + rg * 16 + lhi * 4 + q;
        av[((size_t)i * BSZ + b) * (NH * DH) + nh * DH + dc * 16 + l15] =
            o[rg][dc][q] / lrun[rg][q];
      }
  if (l15 == 0) {
#pragma unroll
    for (int rg = 0; rg < 2; ++rg)
#pragma unroll
      for (int q = 0; q < 4; ++q) {
        int i = i0 + rg * 16 + lhi * 4 + q;
        sm[bn * QLEN + i] = mrun[rg][q];
        srl[bn * QLEN + i] = 1.0f / lrun[rg][q];
      }
  }
}

// ---------------- K2: materialize attn_prob [i][j][b][n] ----------------
// R12 = R11 with store aggregation 2KB -> 8KB bursts (single variable).
// 4 super-phases of 64 j; each = 4x16-j subchunks (R11's K-prefetch pipeline)
// deposited into ONE 64KB LDS tile [16i][64j][32bn] f16, then 16 store passes
// of 8KB fully-contiguous each (512 thr x 16B, linear). Single buffer is safe
// without vmem drains: deposits only need the prior store phase's ds_reads
// done (lgkm barrier); global stores stay in flight. Loads for phase p+1
// issue before phase p's stores -> vmcnt FIFO never drains stores.
#define LOADK(buf, chn)                                                        \
  do {                                                                         \
    _Pragma("unroll") for (int bl_ = 0; bl_ < 4; ++bl_) {                      \
      const f16* Kb_ = Ks + (((size_t)(w4 + bl_)) << 17) +                     \
                       (size_t)(j0 + (chn) * 16 + l15) * DH + lhi * 8;         \
      buf[bl_][0] = *(const f16x8*)(Kb_);                                      \
      buf[bl_][1] = *(const f16x8*)(Kb_ + 32);                                 \
    }                                                                          \
  } while (0)

// compute subchunk ch into stv, issue loads for ch+1, deposit into tile
#define SUBCHUNK(cur, nxt, ch, sub)                                            \
  do {                                                                         \
    f16 stv[4][4];                                                             \
    _Pragma("unroll") for (int bl_ = 0; bl_ < 4; ++bl_) {                      \
      f32x4 z = {0.f, 0.f, 0.f, 0.f};                                          \
      z = mfma16(qf[bl_][0], cur[bl_][0], z);                                  \
      z = mfma16(qf[bl_][1], cur[bl_][1], z);                                  \
      _Pragma("unroll") for (int q_ = 0; q_ < 4; ++q_)                         \
        stv[bl_][q_] = (f16)(__expf(z[q_] * SCALE - mm[bl_][q_]) * rl[bl_][q_]); \
    }                                                                          \
    __builtin_amdgcn_sched_barrier(0);                                         \
    { const int nch_ = ((ch) + 1 < 16) ? (ch) + 1 : 15; LOADK(nxt, nch_); }    \
    __builtin_amdgcn_sched_barrier(0);                                         \
    _Pragma("unroll") for (int q_ = 0; q_ < 4; ++q_) {                         \
      const int i_l = lhi * 4 + q_;                                            \
      const int jl = (sub) * 16 + l15;                                         \
      f16x4 v = {stv[0][q_], stv[1][q_], stv[2][q_], stv[3][q_]};              \
      *(f16x4*)&tile[(i_l * 64 + jl) * 32 + ((w ^ (l15 & 7)) << 2)] = v;       \
    }                                                                          \
  } while (0)

__global__ __launch_bounds__(512, 1) void write_probs(const f16* __restrict__ Qs, const f16* __restrict__ Ks,
                                                      const float* __restrict__ sm, const float* __restrict__ srl,
                                                      float* __restrict__ pout) {
  __shared__ f16 tile[16 * 64 * 32];     // single 64 KiB tile
  const int bid = blockIdx.x;            // 1024 blocks
  const int it = bid >> 3, jt = bid & 7; // jt%8 -> XCD-local K panel
  const int i0 = it << 4, j0 = jt << 8;
  const int t = threadIdx.x, lane = t & 63, w = t >> 6;  // 8 waves, 4 bn each
  const int l15 = lane & 15, lhi = lane >> 4;
  const int w4 = w * 4;

  // hoisted per-block state: Q frags + row stats for this wave's 4 bn
  f16x8 qf[4][2];
  float mm[4][4], rl[4][4];
#pragma unroll
  for (int bl = 0; bl < 4; ++bl) {
    const int bn = w4 + bl;
    const f16* Qb = Qs + ((size_t)bn << 17);
#pragma unroll
    for (int kc = 0; kc < 2; ++kc)
      qf[bl][kc] = *(const f16x8*)&Qb[(size_t)(i0 + l15) * DH + kc * 32 + lhi * 8];
#pragma unroll
    for (int q = 0; q < 4; ++q) {
      const int i = i0 + lhi * 4 + q;
      mm[bl][q] = sm[bn * QLEN + i];
      rl[bl][q] = srl[bn * QLEN + i];
    }
  }

  // store-phase lane mapping: pass r = one i-row, 512 thr x 16B = 8KB linear
  const int j_s = t >> 3;          // j within 64-span, 0..63
  const int o = t & 7;             // bn quad 0..7
  const int swz = o ^ (j_s & 7);

  f16x8 kfA[4][2], kfB[4][2];
  LOADK(kfA, 0);

  for (int ph = 0; ph < 4; ++ph) {
    const int c0 = ph * 4;
    SUBCHUNK(kfA, kfB, c0 + 0, 0);
    SUBCHUNK(kfB, kfA, c0 + 1, 1);
    SUBCHUNK(kfA, kfB, c0 + 2, 2);
    SUBCHUNK(kfB, kfA, c0 + 3, 3);
    barrier_lds();  // all deposits visible; stores may begin
#pragma unroll
    for (int r = 0; r < 16; ++r) {
      f16x4 v = *(const f16x4*)&tile[(r * 64 + j_s) * 32 + (swz << 2)];
      f32x4 ov = {(float)v[0], (float)v[1], (float)v[2], (float)v[3]};
      float* op = pout + ((size_t)(i0 + r) * QLEN + j0 + ph * 64 + j_s) * NBN + o * 4;
      *(f32x4*)op = ov;
    }
    barrier_lds();  // all ds_reads done -> tile reusable; stores keep flying
  }
}

// ---------------- launcher ----------------
extern "C" void kernel_launch(void* const* d_in, const int* in_sizes, int n_in,
                              void* d_out, int out_size, void* d_ws, size_t ws_size,
                              hipStream_t stream) {
  const float* h  = (const float*)d_in[0];
  const float* wq = (const float*)d_in[1];
  float* av   = (float*)d_out;
  float* pout = av + (size_t)QLEN * BSZ * NH * DH;

  char* ws = (char*)d_ws;
  f16* hh  = (f16*)ws;                        // 8 MiB
  f16* wh  = (f16*)(ws + (8u << 20));         // 6 MiB
  f16* Qsc = (f16*)(ws + (16u << 20));        // 8 MiB
  f16* Ksc = (f16*)(ws + (24u << 20));        // 8 MiB
  f16* Vtc = (f16*)(ws + (32u << 20));        // 8 MiB
  float* smv  = (float*)(ws + (40u << 20));
  float* srlv = (float*)(ws + (40u << 20) + (QLEN * NBN * 4));

  const int nh4 = QLEN * BSZ * DM / 4;
  const int nw4 = 3 * NH * DH * DM / 4;
  cvt_f32_f16<<<nh4 / 256, 256, 0, stream>>>(h, hh, nh4);
  cvt_f32_f16<<<nw4 / 256, 256, 0, stream>>>(wq, wh, nw4);
  qkv_gemm<<<32 * 24, 256, 0, stream>>>(hh, wh, Qsc, Ksc, Vtc);
  flash_attn<<<NBN * 16, 256, 0, stream>>>(Qsc, Ksc, Vtc, av, smv, srlv);
  write_probs<<<128 * 8, 512, 0, stream>>>(Qsc, Ksc, smv, srlv, pout);
}